// Round 1
// baseline (1096.317 us; speedup 1.0000x reference)
//
#include <hip/hip_runtime.h>
#include <cstdint>
#include <cstddef>

static constexpr int B_ = 2, S_ = 2048, D_ = 1024, H_ = 16, HD_ = 64;

// ---------------------------------------------------------------------------
// Fused QKV projection: C[4096, 3072] = x[4096,1024] @ {Wq|Wk|Wv} + {bq|bk|bv}
// 128x128 tile, BK=16, 256 threads, 8x8 microtile, fp32 vector FMA.
// ---------------------------------------------------------------------------
__global__ __launch_bounds__(256)
void qkv_gemm(const float* __restrict__ x,
              const float* __restrict__ Wq, const float* __restrict__ bq,
              const float* __restrict__ Wk, const float* __restrict__ bk,
              const float* __restrict__ Wv, const float* __restrict__ bv,
              float* __restrict__ qo, float* __restrict__ ko, float* __restrict__ vo)
{
    const int bx = blockIdx.x;            // 0..23  (3 mats x 8 col-tiles of 128)
    const int by = blockIdx.y;            // 0..31  (row tiles of 128)
    const int mat = bx >> 3;
    const int ncol0 = (bx & 7) * 128;
    const float* __restrict__ W    = (mat == 0) ? Wq : (mat == 1) ? Wk : Wv;
    const float* __restrict__ bias = (mat == 0) ? bq : (mat == 1) ? bk : bv;
    float* __restrict__ O          = (mat == 0) ? qo : (mat == 1) ? ko : vo;

    // Xs stored k-major so the 8-row fragment read is 2x ds_read_b128.
    // 132 stride: 16B-aligned rows (132%4==0), bank-spread for the loads.
    __shared__ __align__(16) float Xs[16][132];  // [kk][row]
    __shared__ __align__(16) float Ws[16][128];  // [kk][col]

    const int t  = threadIdx.x;
    const int tx = t & 15, ty = t >> 4;
    const int rowBase = by * 128;

    float acc[8][8];
    #pragma unroll
    for (int i = 0; i < 8; ++i)
        #pragma unroll
        for (int j = 0; j < 8; ++j) acc[i][j] = 0.f;

    for (int kt = 0; kt < D_; kt += 16) {
        // stage X tile (128 rows x 16 k), k-fastest global reads
        #pragma unroll
        for (int i = 0; i < 8; ++i) {
            int e = t + i * 256;
            int kk = e & 15, r = e >> 4;
            Xs[kk][r] = x[(size_t)(rowBase + r) * D_ + kt + kk];
        }
        // stage W tile (16 k x 128 cols), col-fastest (coalesced)
        #pragma unroll
        for (int i = 0; i < 8; ++i) {
            int e = t + i * 256;
            int kk = e >> 7, c = e & 127;
            Ws[kk][c] = W[(size_t)(kt + kk) * D_ + ncol0 + c];
        }
        __syncthreads();
        #pragma unroll
        for (int kk = 0; kk < 16; ++kk) {
            float4 a0 = *(const float4*)&Xs[kk][ty * 8];
            float4 a1 = *(const float4*)&Xs[kk][ty * 8 + 4];
            float4 b0 = *(const float4*)&Ws[kk][tx * 8];
            float4 b1 = *(const float4*)&Ws[kk][tx * 8 + 4];
            float a[8]  = {a0.x, a0.y, a0.z, a0.w, a1.x, a1.y, a1.z, a1.w};
            float bb[8] = {b0.x, b0.y, b0.z, b0.w, b1.x, b1.y, b1.z, b1.w};
            #pragma unroll
            for (int i = 0; i < 8; ++i)
                #pragma unroll
                for (int j = 0; j < 8; ++j)
                    acc[i][j] += a[i] * bb[j];
        }
        __syncthreads();
    }

    #pragma unroll
    for (int i = 0; i < 8; ++i) {
        const size_t m = (size_t)(rowBase + ty * 8 + i);
        float4 r0, r1;
        r0.x = acc[i][0] + bias[ncol0 + tx * 8 + 0];
        r0.y = acc[i][1] + bias[ncol0 + tx * 8 + 1];
        r0.z = acc[i][2] + bias[ncol0 + tx * 8 + 2];
        r0.w = acc[i][3] + bias[ncol0 + tx * 8 + 3];
        r1.x = acc[i][4] + bias[ncol0 + tx * 8 + 4];
        r1.y = acc[i][5] + bias[ncol0 + tx * 8 + 5];
        r1.z = acc[i][6] + bias[ncol0 + tx * 8 + 6];
        r1.w = acc[i][7] + bias[ncol0 + tx * 8 + 7];
        *(float4*)&O[m * D_ + ncol0 + tx * 8]     = r0;
        *(float4*)&O[m * D_ + ncol0 + tx * 8 + 4] = r1;
    }
}

// ---------------------------------------------------------------------------
// Flash-style masked attention, fp32.
// Reference quirk: masked scores are set to 0.0 BEFORE softmax (not -inf),
// so masked positions contribute exp(0)=1 to the softmax.
// exp() without max-subtraction: scores are O(+-8), fp32 exp is safe and
// mathematically identical to the max-subtracted reference softmax.
// Block = 256 threads = 32 q-rows x 8 lanes; K/V tiled 64 keys at a time.
// ---------------------------------------------------------------------------
__global__ __launch_bounds__(256)
void attn_kernel(const float* __restrict__ q, const float* __restrict__ kmat,
                 const float* __restrict__ vmat, const int* __restrict__ mask,
                 float* __restrict__ out)
{
    const int h  = blockIdx.x;   // head first: 16 heads sharing a mask slice
    const int qt = blockIdx.y;   // dispatch adjacently -> mask hot in L2
    const int b  = blockIdx.z;
    const int t   = threadIdx.x;
    const int row = t >> 3;      // 0..31 q-row within tile
    const int l8  = t & 7;       // 0..7  lane within row-group

    // stride 68: rows 16B-aligned, banks spread (4*idx mod 32)
    __shared__ __align__(16) float Qs[32][68];
    __shared__ __align__(16) float Ks[64][68];
    __shared__ __align__(16) float Vs[64][68];
    __shared__ __align__(16) float Ps[32][68];

    const int q0 = qt * 32;
    const float* __restrict__ qb = q    + (size_t)b * S_ * D_ + h * HD_;
    const float* __restrict__ kb = kmat + (size_t)b * S_ * D_ + h * HD_;
    const float* __restrict__ vb = vmat + (size_t)b * S_ * D_ + h * HD_;
    const int*   __restrict__ mb = mask + (size_t)b * S_ * S_;

    // load Q tile: 32x64
    #pragma unroll
    for (int i = 0; i < 8; ++i) {
        int e = t + i * 256;
        int r = e >> 6, c = e & 63;
        Qs[r][c] = qb[(size_t)(q0 + r) * D_ + c];
    }

    float o0[4] = {0, 0, 0, 0}, o1[4] = {0, 0, 0, 0};
    float lsum = 0.f;

    for (int kt = 0; kt < S_; kt += 64) {
        __syncthreads();  // previous iteration's Ps/Vs reads done
        #pragma unroll
        for (int i = 0; i < 16; ++i) {
            int e = t + i * 256;
            int r = e >> 6, c = e & 63;
            Ks[r][c] = kb[(size_t)(kt + r) * D_ + c];
            Vs[r][c] = vb[(size_t)(kt + r) * D_ + c];
        }
        __syncthreads();

        // scores: this thread owns columns j = jj*8 + l8
        float sc[8] = {0, 0, 0, 0, 0, 0, 0, 0};
        #pragma unroll
        for (int d4 = 0; d4 < 16; ++d4) {
            const float4 qv = *(const float4*)&Qs[row][d4 * 4];
            #pragma unroll
            for (int jj = 0; jj < 8; ++jj) {
                const float4 kv = *(const float4*)&Ks[jj * 8 + l8][d4 * 4];
                sc[jj] += qv.x * kv.x + qv.y * kv.y + qv.z * kv.z + qv.w * kv.w;
            }
        }

        // mask (-> 0), exp, stash P, accumulate row-sum
        const int* __restrict__ mrow = mb + (size_t)(q0 + row) * S_ + kt;
        #pragma unroll
        for (int jj = 0; jj < 8; ++jj) {
            int j = jj * 8 + l8;
            float s = sc[jj] * 0.125f;            // 1/sqrt(64)
            if (mrow[j] != 0) s = 0.f;            // masked -> score 0 (quirk)
            float p = __expf(s);
            lsum += p;
            Ps[row][j] = p;
        }
        __syncthreads();

        // O += P @ V ; this thread owns out dims d = l8*8 .. l8*8+7
        #pragma unroll 8
        for (int j = 0; j < 64; ++j) {
            const float  p  = Ps[row][j];
            const float4 va = *(const float4*)&Vs[j][l8 * 8];
            const float4 vb4 = *(const float4*)&Vs[j][l8 * 8 + 4];
            o0[0] += p * va.x;  o0[1] += p * va.y;
            o0[2] += p * va.z;  o0[3] += p * va.w;
            o1[0] += p * vb4.x; o1[1] += p * vb4.y;
            o1[2] += p * vb4.z; o1[3] += p * vb4.w;
        }
    }

    // total row sum across the 8 lanes of this row (xor of bits 0..2 stays
    // inside the 8-lane group)
    lsum += __shfl_xor(lsum, 1);
    lsum += __shfl_xor(lsum, 2);
    lsum += __shfl_xor(lsum, 4);
    const float inv = 1.0f / lsum;

    float* __restrict__ ob = out + (size_t)b * S_ * D_ + h * HD_;
    float4 r0, r1;
    r0.x = o0[0] * inv; r0.y = o0[1] * inv; r0.z = o0[2] * inv; r0.w = o0[3] * inv;
    r1.x = o1[0] * inv; r1.y = o1[1] * inv; r1.z = o1[2] * inv; r1.w = o1[3] * inv;
    *(float4*)&ob[(size_t)(q0 + row) * D_ + l8 * 8]     = r0;
    *(float4*)&ob[(size_t)(q0 + row) * D_ + l8 * 8 + 4] = r1;
}

extern "C" void kernel_launch(void* const* d_in, const int* in_sizes, int n_in,
                              void* d_out, int out_size, void* d_ws, size_t ws_size,
                              hipStream_t stream) {
    (void)in_sizes; (void)n_in; (void)out_size; (void)ws_size;
    const float* x    = (const float*)d_in[0];
    const int*   mask = (const int*)d_in[1];   // bool -> int32 per harness doc
    const float* Wq   = (const float*)d_in[2];
    const float* bq   = (const float*)d_in[3];
    const float* Wk   = (const float*)d_in[4];
    const float* bk   = (const float*)d_in[5];
    const float* Wv   = (const float*)d_in[6];
    const float* bv   = (const float*)d_in[7];
    float* out = (float*)d_out;

    float* qbuf = (float*)d_ws;                       // 16 MB
    float* kbuf = qbuf + (size_t)B_ * S_ * D_;        // 16 MB
    float* vbuf = kbuf + (size_t)B_ * S_ * D_;        // 16 MB  (48 MB total)

    dim3 g1(24, 32);
    qkv_gemm<<<g1, 256, 0, stream>>>(x, Wq, bq, Wk, bk, Wv, bv, qbuf, kbuf, vbuf);

    dim3 g2(H_, S_ / 32, B_);
    attn_kernel<<<g2, 256, 0, stream>>>(qbuf, kbuf, vbuf, mask, out);
}

// Round 2
// 248.744 us; speedup vs baseline: 4.4074x; 4.4074x over previous
//
#include <hip/hip_runtime.h>
#include <cstdint>
#include <cstddef>

static constexpr int B_ = 2, S_ = 2048, D_ = 1024, H_ = 16, HD_ = 64;

typedef float f32x4 __attribute__((ext_vector_type(4)));
typedef short bf16x8 __attribute__((ext_vector_type(8)));

__device__ __forceinline__ unsigned short f2bf(float f) {
    union { float f; unsigned int u; } v; v.f = f;
    unsigned int r = v.u + 0x7FFFu + ((v.u >> 16) & 1u);   // RNE
    return (unsigned short)(r >> 16);
}
__device__ __forceinline__ float bf2f(unsigned short h) {
    union { unsigned int u; float f; } v; v.u = ((unsigned int)h) << 16;
    return v.f;
}

// ---------------------------------------------------------------------------
// x (fp32, 4M elems) -> bf16, vectorized. grid 2048 x 256, 8 elems/thread.
// ---------------------------------------------------------------------------
__global__ __launch_bounds__(256)
void cast_x(const float* __restrict__ x, unsigned short* __restrict__ o) {
    size_t i = ((size_t)blockIdx.x * 256 + threadIdx.x) * 8;
    float4 a = *(const float4*)(x + i);
    float4 c = *(const float4*)(x + i + 4);
    uint4 r;
    r.x = (unsigned)f2bf(a.x) | ((unsigned)f2bf(a.y) << 16);
    r.y = (unsigned)f2bf(a.z) | ((unsigned)f2bf(a.w) << 16);
    r.z = (unsigned)f2bf(c.x) | ((unsigned)f2bf(c.y) << 16);
    r.w = (unsigned)f2bf(c.z) | ((unsigned)f2bf(c.w) << 16);
    *(uint4*)(o + i) = r;
}

// ---------------------------------------------------------------------------
// Wt[mat][n][k] = bf16(W[mat][k][n]) — 64x64 LDS tile transpose, coalesced
// both directions. grid (16,16,3).
// ---------------------------------------------------------------------------
__global__ __launch_bounds__(256)
void transpose_w(const float* __restrict__ Wq, const float* __restrict__ Wk,
                 const float* __restrict__ Wv, unsigned short* __restrict__ wt) {
    const int mat = blockIdx.z;
    const float* __restrict__ W = (mat == 0) ? Wq : (mat == 1) ? Wk : Wv;
    unsigned short* __restrict__ o = wt + (size_t)mat * D_ * D_;
    const int n0 = blockIdx.x * 64, k0 = blockIdx.y * 64;
    __shared__ unsigned short Ts[64][72];
    const int t = threadIdx.x;
    {
        const int nl = t & 63, kb = t >> 6;
        #pragma unroll
        for (int i = 0; i < 16; ++i) {
            int k = kb + i * 4;
            Ts[nl][k] = f2bf(W[(size_t)(k0 + k) * D_ + n0 + nl]);
        }
    }
    __syncthreads();
    {
        const int kl = t & 63, nb = t >> 6;
        #pragma unroll
        for (int i = 0; i < 16; ++i) {
            int n = nb + i * 4;
            o[(size_t)(n0 + n) * D_ + k0 + kl] = Ts[n][kl];
        }
    }
}

// ---------------------------------------------------------------------------
// QKV GEMM, bf16 MFMA 16x16x32. 128x128 tile, BK=32, 4 waves x (4x4) 16-tiles.
// As/Bs stride 40 bf16 (80B): b128 column reads are <=2-way conflicts (free).
// Outputs q/k/v as bf16 [B*S][D].
// ---------------------------------------------------------------------------
__global__ __launch_bounds__(256)
void qkv_gemm(const unsigned short* __restrict__ xb, const unsigned short* __restrict__ wt,
              const float* __restrict__ bq, const float* __restrict__ bk,
              const float* __restrict__ bv,
              unsigned short* __restrict__ qo, unsigned short* __restrict__ ko,
              unsigned short* __restrict__ vo) {
    const int bx = blockIdx.x;            // 0..23: mat*8 + ntile
    const int by = blockIdx.y;            // 0..31: mtile
    const int mat = bx >> 3;
    const int ncol0 = (bx & 7) * 128;
    const float* __restrict__ bias = (mat == 0) ? bq : (mat == 1) ? bk : bv;
    unsigned short* __restrict__ O = (mat == 0) ? qo : (mat == 1) ? ko : vo;
    const unsigned short* __restrict__ Wm = wt + (size_t)mat * D_ * D_;

    __shared__ unsigned short As[128][40];   // [m][k]  (x rows)
    __shared__ unsigned short Bs[128][40];   // [n][k]  (W^T rows)

    const int t = threadIdx.x;
    const int w = t >> 6, lane = t & 63;
    const int l15 = lane & 15, quad = lane >> 4;
    const int mw = (w >> 1) * 64, nw = (w & 1) * 64;
    const int rowBase = by * 128;

    f32x4 acc[4][4] = {};

    for (int kt = 0; kt < D_; kt += 32) {
        __syncthreads();
        #pragma unroll
        for (int i = 0; i < 2; ++i) {
            int c = t + i * 256;                   // 0..511
            int r = c >> 2, q = c & 3;
            *(uint4*)&As[r][q * 8] =
                *(const uint4*)(xb + (size_t)(rowBase + r) * D_ + kt + q * 8);
            *(uint4*)&Bs[r][q * 8] =
                *(const uint4*)(Wm + (size_t)(ncol0 + r) * D_ + kt + q * 8);
        }
        __syncthreads();

        bf16x8 a[4], b[4];
        #pragma unroll
        for (int i = 0; i < 4; ++i)
            a[i] = *(const bf16x8*)&As[mw + i * 16 + l15][quad * 8];
        #pragma unroll
        for (int j = 0; j < 4; ++j)
            b[j] = *(const bf16x8*)&Bs[nw + j * 16 + l15][quad * 8];
        #pragma unroll
        for (int i = 0; i < 4; ++i)
            #pragma unroll
            for (int j = 0; j < 4; ++j)
                acc[i][j] = __builtin_amdgcn_mfma_f32_16x16x32_bf16(a[i], b[j], acc[i][j], 0, 0, 0);
    }

    // epilogue: bias + cast + store (C/D layout: col=lane&15, row=quad*4+reg)
    #pragma unroll
    for (int j = 0; j < 4; ++j) {
        const int col = ncol0 + nw + j * 16 + l15;
        const float bb = bias[col];
        #pragma unroll
        for (int i = 0; i < 4; ++i) {
            #pragma unroll
            for (int r = 0; r < 4; ++r) {
                const int m = rowBase + mw + i * 16 + quad * 4 + r;
                O[(size_t)m * D_ + col] = f2bf(acc[i][j][r] + bb);
            }
        }
    }
}

// ---------------------------------------------------------------------------
// Flash attention, bf16 MFMA. Q-tile 128 (4 wave-private 32-row strips),
// K/V-tile 64. Mask quirk: masked score -> 0 -> p = exp(0) = 1.
// P round-trips LDS (C-layout -> A-layout); V staged transposed for B-operand.
// All LDS arrays stride 72 bf16 (144B) -> b128 reads <=2-way (free).
// ---------------------------------------------------------------------------
__global__ __launch_bounds__(256)
void attn_mfma(const unsigned short* __restrict__ qmat,
               const unsigned short* __restrict__ kmat,
               const unsigned short* __restrict__ vmat,
               const int* __restrict__ mask, float* __restrict__ out) {
    const int h = blockIdx.x, qt = blockIdx.y, b = blockIdx.z;
    const int t = threadIdx.x, w = t >> 6, lane = t & 63;
    const int l15 = lane & 15, quad = lane >> 4;
    const int q0 = qt * 128;

    __shared__ unsigned short Qs[128][72];   // [qrow][d]
    __shared__ unsigned short Ks[64][72];    // [key][d]
    __shared__ unsigned short Vt[64][72];    // [d][key]  (transposed)
    __shared__ unsigned short Ps[128][72];   // [qrow][key] wave-private strips

    const size_t bh = (size_t)b * S_ * D_ + (size_t)h * HD_;
    const unsigned short* __restrict__ qp = qmat + bh;
    const unsigned short* __restrict__ kp = kmat + bh;
    const unsigned short* __restrict__ vp = vmat + bh;
    const int* __restrict__ mb = mask + (size_t)b * S_ * S_;

    // stage Q tile (128 x 64)
    #pragma unroll
    for (int i = 0; i < 4; ++i) {
        int c = t + i * 256;                 // 0..1023
        int r = c >> 3, q8 = c & 7;
        *(uint4*)&Qs[r][q8 * 8] = *(const uint4*)(qp + (size_t)(q0 + r) * D_ + q8 * 8);
    }

    f32x4 accO[2][4] = {};
    float lsum[2][4] = {};

    for (int kt = 0; kt < S_; kt += 64) {
        __syncthreads();                     // protect Ks/Vt from prior readers
        #pragma unroll
        for (int i = 0; i < 2; ++i) {
            int c = t + i * 256;             // 0..511
            int r = c >> 3, q8 = c & 7;
            *(uint4*)&Ks[r][q8 * 8] = *(const uint4*)(kp + (size_t)(kt + r) * D_ + q8 * 8);
        }
        {   // V transposed: thread t covers s = t&63, d in [d0, d0+16)
            const int s = t & 63, d0 = (t >> 6) * 16;
            #pragma unroll
            for (int half = 0; half < 2; ++half) {
                uint4 v = *(const uint4*)(vp + (size_t)(kt + s) * D_ + d0 + half * 8);
                const unsigned short* pv = (const unsigned short*)&v;
                #pragma unroll
                for (int j = 0; j < 8; ++j) Vt[d0 + half * 8 + j][s] = pv[j];
            }
        }
        __syncthreads();

        // S = Q K^T  (m: 2x16 wave strip rows, n: 64 keys, k: d=64)
        f32x4 sc[2][4] = {};
        #pragma unroll
        for (int kst = 0; kst < 2; ++kst) {
            bf16x8 bfr[4];
            #pragma unroll
            for (int nt = 0; nt < 4; ++nt)
                bfr[nt] = *(const bf16x8*)&Ks[nt * 16 + l15][kst * 32 + quad * 8];
            #pragma unroll
            for (int mt = 0; mt < 2; ++mt) {
                bf16x8 afr = *(const bf16x8*)&Qs[w * 32 + mt * 16 + l15][kst * 32 + quad * 8];
                #pragma unroll
                for (int nt = 0; nt < 4; ++nt)
                    sc[mt][nt] = __builtin_amdgcn_mfma_f32_16x16x32_bf16(afr, bfr[nt], sc[mt][nt], 0, 0, 0);
            }
        }

        // mask + exp + stash P (bf16); lsum from bf16-rounded p for consistency
        #pragma unroll
        for (int mt = 0; mt < 2; ++mt) {
            #pragma unroll
            for (int r = 0; r < 4; ++r) {
                const int lrow = w * 32 + mt * 16 + quad * 4 + r;
                const int* __restrict__ mr = mb + (size_t)(q0 + lrow) * S_ + kt;
                float ls = 0.f;
                #pragma unroll
                for (int nt = 0; nt < 4; ++nt) {
                    const int cc = nt * 16 + l15;
                    float s = sc[mt][nt][r] * 0.125f;        // 1/sqrt(64)
                    float p = (mr[cc] != 0) ? 1.0f : __expf(s);
                    unsigned short pb = f2bf(p);
                    Ps[lrow][cc] = pb;
                    ls += bf2f(pb);
                }
                lsum[mt][r] += ls;
            }
        }

        // O += P V   (Ps strips are wave-private: no barrier needed)
        #pragma unroll
        for (int kst = 0; kst < 2; ++kst) {
            bf16x8 bfr[4];
            #pragma unroll
            for (int dt = 0; dt < 4; ++dt)
                bfr[dt] = *(const bf16x8*)&Vt[dt * 16 + l15][kst * 32 + quad * 8];
            #pragma unroll
            for (int mt = 0; mt < 2; ++mt) {
                bf16x8 afr = *(const bf16x8*)&Ps[w * 32 + mt * 16 + l15][kst * 32 + quad * 8];
                #pragma unroll
                for (int dt = 0; dt < 4; ++dt)
                    accO[mt][dt] = __builtin_amdgcn_mfma_f32_16x16x32_bf16(afr, bfr[dt], accO[mt][dt], 0, 0, 0);
            }
        }
    }

    // normalize + store (fp32 out)
    float* __restrict__ ob = out + ((size_t)b * S_ + q0) * D_ + (size_t)h * HD_;
    #pragma unroll
    for (int mt = 0; mt < 2; ++mt) {
        #pragma unroll
        for (int r = 0; r < 4; ++r) {
            float v = lsum[mt][r];
            v += __shfl_xor(v, 1);
            v += __shfl_xor(v, 2);
            v += __shfl_xor(v, 4);
            v += __shfl_xor(v, 8);
            const float inv = 1.0f / v;
            const int lrow = w * 32 + mt * 16 + quad * 4 + r;
            #pragma unroll
            for (int dt = 0; dt < 4; ++dt)
                ob[(size_t)lrow * D_ + dt * 16 + l15] = accO[mt][dt][r] * inv;
        }
    }
}

extern "C" void kernel_launch(void* const* d_in, const int* in_sizes, int n_in,
                              void* d_out, int out_size, void* d_ws, size_t ws_size,
                              hipStream_t stream) {
    (void)in_sizes; (void)n_in; (void)out_size; (void)ws_size;
    const float* x    = (const float*)d_in[0];
    const int*   mask = (const int*)d_in[1];
    const float* Wq   = (const float*)d_in[2];
    const float* bq   = (const float*)d_in[3];
    const float* Wk   = (const float*)d_in[4];
    const float* bk   = (const float*)d_in[5];
    const float* Wv   = (const float*)d_in[6];
    const float* bv   = (const float*)d_in[7];
    float* out = (float*)d_out;

    unsigned short* xb = (unsigned short*)d_ws;                 // 4M bf16 = 8 MB
    unsigned short* wt = xb + (size_t)4 * 1024 * 1024;          // 3M bf16 = 6 MB
    unsigned short* qb = wt + (size_t)3 * 1024 * 1024;          // 4M bf16 = 8 MB
    unsigned short* kb = qb + (size_t)4 * 1024 * 1024;          // 8 MB
    unsigned short* vb = kb + (size_t)4 * 1024 * 1024;          // 8 MB (38 MB total)

    cast_x<<<2048, 256, 0, stream>>>(x, xb);
    transpose_w<<<dim3(16, 16, 3), 256, 0, stream>>>(Wq, Wk, Wv, wt);
    qkv_gemm<<<dim3(24, 32), 256, 0, stream>>>(xb, wt, bq, bk, bv, qb, kb, vb);
    attn_mfma<<<dim3(16, 16, 2), 256, 0, stream>>>(qb, kb, vb, mask, out);
}